// Round 1
// baseline (318.716 us; speedup 1.0000x reference)
//
#include <hip/hip_runtime.h>

#define BB 8
#define NN 2048
#define DIN 128
#define DOUT 64
#define ALPHA_NS 0.2f
#define NEG_BIG -9000000000000000.0f
#define ITILE 16
#define JTILE 64
#define NWAVE 4

// ---------------- Kernel A: z = h @ W, s1 = z.a1, s2 = z.a2 ----------------
__global__ __launch_bounds__(256) void gat_zproj(
    const float* __restrict__ h, const float* __restrict__ W,
    const float* __restrict__ a, float* __restrict__ z,
    float* __restrict__ s1, float* __restrict__ s2) {
  const int lane = threadIdx.x & 63;
  const int wv = threadIdx.x >> 6;
  const long row = (long)blockIdx.x * 4 + wv;   // one wave per row
  const float* hrow = h + row * DIN;
  float acc = 0.f;
#pragma unroll
  for (int k4 = 0; k4 < DIN / 4; ++k4) {
    const float4 h4 = *reinterpret_cast<const float4*>(hrow + k4 * 4);
    acc = fmaf(h4.x, W[(k4 * 4 + 0) * DOUT + lane], acc);
    acc = fmaf(h4.y, W[(k4 * 4 + 1) * DOUT + lane], acc);
    acc = fmaf(h4.z, W[(k4 * 4 + 2) * DOUT + lane], acc);
    acc = fmaf(h4.w, W[(k4 * 4 + 3) * DOUT + lane], acc);
  }
  z[row * DOUT + lane] = acc;
  float v1 = acc * a[lane];
  float v2 = acc * a[DOUT + lane];
#pragma unroll
  for (int off = 32; off; off >>= 1) {
    v1 += __shfl_xor(v1, off);
    v2 += __shfl_xor(v2, off);
  }
  if (lane == 0) { s1[row] = v1; s2[row] = v2; }
}

// ---------------- Kernel A2: zmean[b][d] = mean_j z[b][j][d] ----------------
// (needed for fully-masked rows: softmax of a constant -9e15 row is uniform)
__global__ __launch_bounds__(256) void gat_zmean(
    const float* __restrict__ z, float* __restrict__ zmean) {
  const int b = blockIdx.x;
  const int lane = threadIdx.x & 63;
  const int wv = threadIdx.x >> 6;
  float s = 0.f;
  for (int j = wv; j < NN; j += 4)
    s += z[((long)b * NN + j) * DOUT + lane];
  __shared__ float red[4][DOUT];
  red[wv][lane] = s;
  __syncthreads();
  if (wv == 0)
    zmean[b * DOUT + lane] =
        (red[0][lane] + red[1][lane] + red[2][lane] + red[3][lane]) * (1.f / NN);
}

// ---------------- Kernel B: masked softmax + PV + ELU ----------------
// grid = (N/16, B); block = 256 (4 waves). Each block: 16 i-rows.
// Each wave owns an interleaved j-stripe (8 tiles of 64 j).
// Fixed softmax shift m=0 (scores bounded; exp cannot overflow).
// Fully-masked rows => denominator exactly 0 => fall back to zmean.
__global__ __launch_bounds__(256) void gat_attn(
    const float* __restrict__ z, const float* __restrict__ s1g,
    const float* __restrict__ s2g, const int* __restrict__ adj,
    const int* __restrict__ mask, const float* __restrict__ zmean,
    float* __restrict__ out) {
  const int b = blockIdx.y;
  const int i0 = blockIdx.x * ITILE;
  const int tid = threadIdx.x;
  const int w = tid >> 6;
  const int lane = tid & 63;
  const int d4 = lane & 15;   // dim quad: dims d4*4 .. d4*4+3
  const int iq = lane >> 4;   // i quad:  rows iq*4 .. iq*4+3

  __shared__ float sbuf[NWAVE * JTILE * ITILE];  // 16 KB: pT, later aliased as accS
  float (*pT)[JTILE][ITILE] = reinterpret_cast<float(*)[JTILE][ITILE]>(sbuf);
  float (*accS)[ITILE][DOUT] = reinterpret_cast<float(*)[ITILE][DOUT]>(sbuf);
  __shared__ float Lred[NWAVE][ITILE];
  __shared__ float s1s[ITILE];
  __shared__ int mis[ITILE];

  if (tid < ITILE) {
    s1s[tid] = s1g[(long)b * NN + i0 + tid];
    mis[tid] = mask[b * NN + i0 + tid];
  }
  __syncthreads();

  float acc[4][4];
#pragma unroll
  for (int ai = 0; ai < 4; ++ai)
#pragma unroll
    for (int c = 0; c < 4; ++c) acc[ai][c] = 0.f;
  float lpart[ITILE];
#pragma unroll
  for (int i = 0; i < ITILE; ++i) lpart[i] = 0.f;

  const float* zb = z + (long)b * NN * DOUT;

  for (int t = 0; t < NN / (JTILE * NWAVE); ++t) {  // 8 tiles per wave
    const int j0 = (t * NWAVE + w) * JTILE;
    // ---- phase 1: p for 16 i x 64 j (lane = j) ----
    const float s2j = s2g[(long)b * NN + j0 + lane];
    const int mj = mask[b * NN + j0 + lane];
    const int* adjp = adj + ((long)b * NN + i0) * NN + j0 + lane;
    float p[ITILE];
#pragma unroll
    for (int i = 0; i < ITILE; ++i) {
      const int aij = adjp[(long)i * NN];
      float e = s1s[i] + s2j;
      e = e > 0.f ? e : ALPHA_NS * e;
      e = ((aij & mj & mis[i]) != 0) ? e : NEG_BIG;
      const float pv = __expf(e);   // exp(-9e15) underflows to exactly 0
      p[i] = pv;
      lpart[i] += pv;
    }
    float* pw = &pT[w][lane][0];
#pragma unroll
    for (int q = 0; q < 4; ++q)
      *reinterpret_cast<float4*>(pw + q * 4) =
          make_float4(p[q * 4], p[q * 4 + 1], p[q * 4 + 2], p[q * 4 + 3]);
    // LDS ops within a wave complete in order; pT[w] is wave-private -> no barrier.
    // ---- phase 2: acc[i][d] += p[i][jj] * z[jj][d] ----
#pragma unroll 4
    for (int jj = 0; jj < JTILE; ++jj) {
      const float4 pv = *reinterpret_cast<const float4*>(&pT[w][jj][iq * 4]);
      const float4 zv =
          *reinterpret_cast<const float4*>(zb + (long)(j0 + jj) * DOUT + d4 * 4);
      const float pa[4] = {pv.x, pv.y, pv.z, pv.w};
      const float zc[4] = {zv.x, zv.y, zv.z, zv.w};
#pragma unroll
      for (int ai = 0; ai < 4; ++ai)
#pragma unroll
        for (int c = 0; c < 4; ++c)
          acc[ai][c] = fmaf(pa[ai], zc[c], acc[ai][c]);
    }
  }

  // ---- merge: denominator over lanes, then across waves via LDS ----
#pragma unroll
  for (int i = 0; i < ITILE; ++i)
#pragma unroll
    for (int off = 32; off; off >>= 1) lpart[i] += __shfl_xor(lpart[i], off);
  if (lane == 0) {
#pragma unroll
    for (int i = 0; i < ITILE; ++i) Lred[w][i] = lpart[i];
  }
  // write partial acc into accS (aliases this wave's own pT slice; wave-local, in-order)
#pragma unroll
  for (int ai = 0; ai < 4; ++ai) {
    const float4 v = make_float4(acc[ai][0], acc[ai][1], acc[ai][2], acc[ai][3]);
    *reinterpret_cast<float4*>(&accS[w][iq * 4 + ai][d4 * 4]) = v;
  }
  __syncthreads();

  // ---- epilogue: combine 4 waves, divide, ELU, store ----
  const float* zm = zmean + b * DOUT;
#pragma unroll
  for (int it = 0; it < 4; ++it) {
    const int i = (tid >> 6) + it * 4;
    const int d = tid & 63;
    const float L = Lred[0][i] + Lred[1][i] + Lred[2][i] + Lred[3][i];
    const float v = accS[0][i][d] + accS[1][i][d] + accS[2][i][d] + accS[3][i][d];
    const float hp = (L != 0.f) ? (v / L) : zm[d];
    const float r = hp > 0.f ? hp : (__expf(hp) - 1.f);
    out[((long)b * NN + i0 + i) * DOUT + d] = r;
  }
}

extern "C" void kernel_launch(void* const* d_in, const int* in_sizes, int n_in,
                              void* d_out, int out_size, void* d_ws, size_t ws_size,
                              hipStream_t stream) {
  const float* h = (const float*)d_in[0];
  const int* adj = (const int*)d_in[1];
  const int* mask = (const int*)d_in[2];
  const float* W = (const float*)d_in[3];
  const float* a = (const float*)d_in[4];
  float* out = (float*)d_out;

  float* z = (float*)d_ws;                      // B*N*DOUT   = 1,048,576 f
  float* s1 = z + (size_t)BB * NN * DOUT;       // B*N        = 16,384 f
  float* s2 = s1 + (size_t)BB * NN;             // B*N        = 16,384 f
  float* zmean = s2 + (size_t)BB * NN;          // B*DOUT     = 512 f   (~4.33 MB total)

  gat_zproj<<<dim3(BB * NN / 4), dim3(256), 0, stream>>>(h, W, a, z, s1, s2);
  gat_zmean<<<dim3(BB), dim3(256), 0, stream>>>(z, zmean);
  gat_attn<<<dim3(NN / ITILE, BB), dim3(256), 0, stream>>>(z, s1, s2, adj, mask,
                                                           zmean, out);
}

// Round 2
// 155.441 us; speedup vs baseline: 2.0504x; 2.0504x over previous
//
#include <hip/hip_runtime.h>

#define BB 8
#define NN 2048
#define DIN 128
#define DOUT 64
#define ALPHA_NS 0.2f
#define ITILE 16
#define JTILE 64
#define NWAVE 4

typedef __attribute__((ext_vector_type(4))) short short4v;
typedef __attribute__((ext_vector_type(4))) unsigned short ushort4v;
typedef __attribute__((ext_vector_type(4))) float float4v;

__device__ __forceinline__ unsigned short f32_to_bf16_rne(float x) {
  unsigned u = __builtin_bit_cast(unsigned, x);
  u += 0x7FFFu + ((u >> 16) & 1u);
  return (unsigned short)(u >> 16);
}
__device__ __forceinline__ float bf16_to_f32(unsigned short s) {
  unsigned u = ((unsigned)s) << 16;
  return __builtin_bit_cast(float, u);
}

// ------ Kernel A: z = h@W (fp32 acc), emits zT(bf16), s1, s2, zsum ------
// grid = B*N/16 blocks, 256 thr. Wave w holds W[k=w*32..w*32+31][:] in regs.
__global__ __launch_bounds__(256) void gat_zproj(
    const float* __restrict__ h, const float* __restrict__ W,
    const float* __restrict__ a, unsigned short* __restrict__ zT,
    float* __restrict__ s1, float* __restrict__ s2, float* __restrict__ zsum) {
  const int tid = threadIdx.x;
  const int w = tid >> 6, lane = tid & 63;
  const long r0 = (long)blockIdx.x * 16;
  const int b = blockIdx.x >> 7;  // 128 blocks per batch

  __shared__ float hS[16][DIN];       // 8 KB
  __shared__ float accW[4][16][DOUT]; // 16 KB
  __shared__ float zred[4][DOUT];     // 1 KB

  float Wr[32];
#pragma unroll
  for (int kk = 0; kk < 32; ++kk) Wr[kk] = W[(w * 32 + kk) * DOUT + lane];

  {
    const int r = tid >> 4, c = (tid & 15) * 8;
    const float* src = h + (r0 + r) * DIN + c;
    *reinterpret_cast<float4*>(&hS[r][c]) = *reinterpret_cast<const float4*>(src);
    *reinterpret_cast<float4*>(&hS[r][c + 4]) =
        *reinterpret_cast<const float4*>(src + 4);
  }
  __syncthreads();

#pragma unroll
  for (int r = 0; r < 16; ++r) {
    float acc = 0.f;
#pragma unroll
    for (int k4 = 0; k4 < 8; ++k4) {
      const float4 h4 = *reinterpret_cast<const float4*>(&hS[r][w * 32 + k4 * 4]);
      acc = fmaf(h4.x, Wr[k4 * 4 + 0], acc);
      acc = fmaf(h4.y, Wr[k4 * 4 + 1], acc);
      acc = fmaf(h4.z, Wr[k4 * 4 + 2], acc);
      acc = fmaf(h4.w, Wr[k4 * 4 + 3], acc);
    }
    accW[w][r][lane] = acc;
  }
  __syncthreads();

  // epilogue: wave w -> rows w*4..w*4+3 (consecutive, enables packed zT store)
  float zsp = 0.f;
  unsigned short zt4[4];
#pragma unroll
  for (int it = 0; it < 4; ++it) {
    const int i = w * 4 + it;
    const int d = lane;
    const float zv =
        accW[0][i][d] + accW[1][i][d] + accW[2][i][d] + accW[3][i][d];
    zsp += zv;
    zt4[it] = f32_to_bf16_rne(zv);
    float v1 = zv * a[d];
    float v2 = zv * a[DOUT + d];
#pragma unroll
    for (int off = 32; off; off >>= 1) {
      v1 += __shfl_xor(v1, off);
      v2 += __shfl_xor(v2, off);
    }
    if (lane == 0) {
      s1[r0 + i] = v1;
      s2[r0 + i] = v2;
    }
  }
  // zT[d][j] : lane=d, rows r0+w*4.. -> one 8B store
  {
    ushort4v v;
    v.x = zt4[0]; v.y = zt4[1]; v.z = zt4[2]; v.w = zt4[3];
    *reinterpret_cast<ushort4v*>(zT + (size_t)lane * (BB * NN) + r0 + w * 4) = v;
  }
  // zsum partial (for fully-masked-row fallback)
  zred[w][lane] = zsp;
  __syncthreads();
  if (w == 0)
    atomicAdd(&zsum[b * DOUT + lane],
              zred[0][lane] + zred[1][lane] + zred[2][lane] + zred[3][lane]);
}

// ------ Kernel B: masked softmax + PV (bf16 MFMA) + ELU ------
// grid = (N/16, B), 256 thr. Wave w owns interleaved j-stripes of 64.
__global__ __launch_bounds__(256) void gat_attn(
    const unsigned short* __restrict__ zT, const float* __restrict__ s1g,
    const float* __restrict__ s2g, const int* __restrict__ adj,
    const int* __restrict__ mask, const float* __restrict__ zsum,
    float* __restrict__ out) {
  const int b = blockIdx.y;
  const int i0 = blockIdx.x * ITILE;
  const int tid = threadIdx.x;
  const int w = tid >> 6, lane = tid & 63;
  const int row16 = lane & 15, kgrp = lane >> 4;

  __shared__ unsigned short pA[NWAVE][ITILE][72];  // 9.2 KB (+8 pad: 2-way max)
  __shared__ float accS[NWAVE][ITILE][DOUT];       // 16 KB
  __shared__ float Lred[NWAVE][ITILE];
  __shared__ float s1s[ITILE];
  __shared__ int mis[ITILE];

  if (tid < ITILE) {
    s1s[tid] = s1g[b * NN + i0 + tid];
    mis[tid] = mask[b * NN + i0 + tid];
  }
  __syncthreads();

  float4v acc[4];
#pragma unroll
  for (int dt = 0; dt < 4; ++dt) acc[dt] = (float4v){0.f, 0.f, 0.f, 0.f};
  float lpart[ITILE];
#pragma unroll
  for (int i = 0; i < ITILE; ++i) lpart[i] = 0.f;

  for (int t = 0; t < NN / (JTILE * NWAVE); ++t) {
    const int j0 = (t * NWAVE + w) * JTILE;
    // ---- phase 1: scores -> p (bf16) into pA[w][i][j], lane = j ----
    const float s2j = s2g[b * NN + j0 + lane];
    const int mj = mask[b * NN + j0 + lane];
    const int* adjp = adj + ((long)(b * NN + i0)) * NN + j0 + lane;
#pragma unroll
    for (int i = 0; i < ITILE; ++i) {
      const int aij = adjp[(long)i * NN];
      float e = s1s[i] + s2j;
      e = e > 0.f ? e : ALPHA_NS * e;
      const bool ok = (aij & mj & mis[i]) != 0;
      float pv = ok ? __expf(e) : 0.f;
      const unsigned short pb = f32_to_bf16_rne(pv);
      pA[w][i][lane] = pb;
      lpart[i] += bf16_to_f32(pb);  // rounded p in denom: common-mode with num
    }
    // ---- phase 2: acc[i][d] += P[i][k] * Z[k][d] via 16x16x16 bf16 MFMA ----
#pragma unroll
    for (int ks = 0; ks < 4; ++ks) {
      const int jloc = ks * 16 + kgrp * 4;
      const short4v af = __builtin_bit_cast(
          short4v, *reinterpret_cast<const ushort4v*>(&pA[w][row16][jloc]));
#pragma unroll
      for (int dt = 0; dt < 4; ++dt) {
        const unsigned short* bp = zT + (size_t)(dt * 16 + row16) * (BB * NN) +
                                   (size_t)b * NN + j0 + jloc;
        const short4v bf = __builtin_bit_cast(
            short4v, *reinterpret_cast<const ushort4v*>(bp));
        acc[dt] =
            __builtin_amdgcn_mfma_f32_16x16x16bf16_1k(af, bf, acc[dt], 0, 0, 0);
      }
    }
  }

  // ---- reduce denominators across lanes, stash partials ----
#pragma unroll
  for (int i = 0; i < ITILE; ++i)
#pragma unroll
    for (int off = 32; off; off >>= 1) lpart[i] += __shfl_xor(lpart[i], off);
  if (lane == 0) {
#pragma unroll
    for (int i = 0; i < ITILE; ++i) Lred[w][i] = lpart[i];
  }
#pragma unroll
  for (int dt = 0; dt < 4; ++dt) {
#pragma unroll
    for (int r = 0; r < 4; ++r)
      accS[w][kgrp * 4 + r][dt * 16 + row16] = acc[dt][r];
  }
  __syncthreads();

  // ---- epilogue: combine waves, divide, ELU, store ----
#pragma unroll
  for (int it = 0; it < 4; ++it) {
    const int i = (tid >> 6) + it * 4;
    const int d = tid & 63;
    const float L = Lred[0][i] + Lred[1][i] + Lred[2][i] + Lred[3][i];
    const float v = accS[0][i][d] + accS[1][i][d] + accS[2][i][d] + accS[3][i][d];
    const float hp = (L != 0.f) ? (v / L) : (zsum[b * DOUT + d] * (1.f / NN));
    const float r = hp > 0.f ? hp : (__expf(hp) - 1.f);
    out[((long)b * NN + i0 + i) * DOUT + d] = r;
  }
}

extern "C" void kernel_launch(void* const* d_in, const int* in_sizes, int n_in,
                              void* d_out, int out_size, void* d_ws, size_t ws_size,
                              hipStream_t stream) {
  const float* h = (const float*)d_in[0];
  const int* adj = (const int*)d_in[1];
  const int* mask = (const int*)d_in[2];
  const float* W = (const float*)d_in[3];
  const float* a = (const float*)d_in[4];
  float* out = (float*)d_out;

  unsigned short* zT = (unsigned short*)d_ws;               // 64 * 16384 * 2B = 2 MB
  float* s1 = (float*)((char*)d_ws + (size_t)DOUT * BB * NN * 2);
  float* s2 = s1 + (size_t)BB * NN;
  float* zsum = s2 + (size_t)BB * NN;                       // B*DOUT floats

  hipMemsetAsync(zsum, 0, BB * DOUT * sizeof(float), stream);
  gat_zproj<<<dim3(BB * NN / 16), dim3(256), 0, stream>>>(h, W, a, zT, s1, s2,
                                                          zsum);
  gat_attn<<<dim3(NN / ITILE, BB), dim3(256), 0, stream>>>(zT, s1, s2, adj, mask,
                                                           zsum, out);
}

// Round 3
// 103.115 us; speedup vs baseline: 3.0909x; 1.5074x over previous
//
#include <hip/hip_runtime.h>

#define BB 8
#define NN 2048
#define DIN 128
#define DOUT 64
#define ALPHA_NS 0.2f
#define ITILE 16
#define JTILE 64
#define NWAVE 4
#define DEXT 80  // 64 z dims + 16 extra rows (row 64 = ones for denominator)

typedef __attribute__((ext_vector_type(4))) short short4v;
typedef __attribute__((ext_vector_type(4))) unsigned short ushort4v;
typedef __attribute__((ext_vector_type(4))) float float4v;

__device__ __forceinline__ unsigned short f32_to_bf16_rne(float x) {
  unsigned u = __builtin_bit_cast(unsigned, x);
  u += 0x7FFFu + ((u >> 16) & 1u);
  return (unsigned short)(u >> 16);
}

// ------ Kernel A: z = h@W (fp32 acc), emits zT(bf16, 80 rows), s1, s2, zsum ---
__global__ __launch_bounds__(256) void gat_zproj(
    const float* __restrict__ h, const float* __restrict__ W,
    const float* __restrict__ a, unsigned short* __restrict__ zT,
    float* __restrict__ s1, float* __restrict__ s2, float* __restrict__ zsum) {
  const int tid = threadIdx.x;
  const int w = tid >> 6, lane = tid & 63;
  const long r0 = (long)blockIdx.x * 16;
  const int b = blockIdx.x >> 7;  // 128 blocks per batch

  __shared__ float hS[16][DIN];       // 8 KB
  __shared__ float accW[4][16][DOUT]; // 16 KB
  __shared__ float zred[4][DOUT];     // 1 KB

  float Wr[32];
#pragma unroll
  for (int kk = 0; kk < 32; ++kk) Wr[kk] = W[(w * 32 + kk) * DOUT + lane];

  {
    const int r = tid >> 4, c = (tid & 15) * 8;
    const float* src = h + (r0 + r) * DIN + c;
    *reinterpret_cast<float4*>(&hS[r][c]) = *reinterpret_cast<const float4*>(src);
    *reinterpret_cast<float4*>(&hS[r][c + 4]) =
        *reinterpret_cast<const float4*>(src + 4);
  }
  // init zT rows 64..79 for this block's column slice (row 64 = 1.0 bf16)
  {
    const int rr = 64 + (tid >> 4), cc = (int)r0 + (tid & 15);
    zT[(size_t)rr * (BB * NN) + cc] = (rr == 64) ? 0x3F80 : 0;
  }
  __syncthreads();

#pragma unroll
  for (int r = 0; r < 16; ++r) {
    float acc = 0.f;
#pragma unroll
    for (int k4 = 0; k4 < 8; ++k4) {
      const float4 h4 = *reinterpret_cast<const float4*>(&hS[r][w * 32 + k4 * 4]);
      acc = fmaf(h4.x, Wr[k4 * 4 + 0], acc);
      acc = fmaf(h4.y, Wr[k4 * 4 + 1], acc);
      acc = fmaf(h4.z, Wr[k4 * 4 + 2], acc);
      acc = fmaf(h4.w, Wr[k4 * 4 + 3], acc);
    }
    accW[w][r][lane] = acc;
  }
  __syncthreads();

  float zsp = 0.f;
  unsigned short zt4[4];
#pragma unroll
  for (int it = 0; it < 4; ++it) {
    const int i = w * 4 + it;
    const int d = lane;
    const float zv =
        accW[0][i][d] + accW[1][i][d] + accW[2][i][d] + accW[3][i][d];
    zsp += zv;
    zt4[it] = f32_to_bf16_rne(zv);
    float v1 = zv * a[d];
    float v2 = zv * a[DOUT + d];
#pragma unroll
    for (int off = 32; off; off >>= 1) {
      v1 += __shfl_xor(v1, off);
      v2 += __shfl_xor(v2, off);
    }
    if (lane == 0) {
      s1[r0 + i] = v1;
      s2[r0 + i] = v2;
    }
  }
  {
    ushort4v v;
    v.x = zt4[0]; v.y = zt4[1]; v.z = zt4[2]; v.w = zt4[3];
    *reinterpret_cast<ushort4v*>(zT + (size_t)lane * (BB * NN) + r0 + w * 4) = v;
  }
  zred[w][lane] = zsp;
  __syncthreads();
  if (w == 0)
    atomicAdd(&zsum[b * DOUT + lane],
              zred[0][lane] + zred[1][lane] + zred[2][lane] + zred[3][lane]);
}

// ------ Kernel B: masked softmax + PV (bf16 MFMA) + ELU, pipelined ------
__global__ __launch_bounds__(256) void gat_attn(
    const unsigned short* __restrict__ zT, const float* __restrict__ s1g,
    const float* __restrict__ s2g, const int* __restrict__ adj,
    const int* __restrict__ mask, const float* __restrict__ zsum,
    float* __restrict__ out) {
  const int b = blockIdx.y;
  const int i0 = blockIdx.x * ITILE;
  const int tid = threadIdx.x;
  const int w = tid >> 6, lane = tid & 63;
  const int row16 = lane & 15, kgrp = lane >> 4;

  __shared__ unsigned short pA[NWAVE][ITILE][72];  // 9.2 KB
  __shared__ float accS[NWAVE][ITILE][DOUT];       // 16 KB
  __shared__ float Lred[NWAVE][ITILE];
  __shared__ float s1s[ITILE];
  __shared__ int mis[ITILE];

  if (tid < ITILE) {
    s1s[tid] = s1g[b * NN + i0 + tid];
    mis[tid] = mask[b * NN + i0 + tid];
  }
  __syncthreads();

  // zero pA rows for masked-out i once (they never change)
#pragma unroll
  for (int i = 0; i < ITILE; ++i)
    if (!mis[i]) pA[w][i][lane] = 0;

  float4v acc[5];
#pragma unroll
  for (int dt = 0; dt < 5; ++dt) acc[dt] = (float4v){0.f, 0.f, 0.f, 0.f};

  const int* adjp = adj + ((long)(b * NN + i0)) * NN;
  const unsigned short* zb = zT + (size_t)b * NN;

  // ---- prologue: prefetch tile 0 ----
  int aij[ITILE];
  {
    const int j0 = w * JTILE;
#pragma unroll
    for (int i = 0; i < ITILE; ++i)
      if (mis[i]) aij[i] = adjp[(long)i * NN + j0 + lane];
  }
  float s2j = s2g[b * NN + w * JTILE + lane];
  int mj = mask[b * NN + w * JTILE + lane];

#pragma unroll 1
  for (int t = 0; t < NN / (JTILE * NWAVE); ++t) {
    const int j0c = (t * NWAVE + w) * JTILE;
    // ---- phase 1: scores -> p (bf16) into pA[w][i][j] using prefetched regs --
#pragma unroll
    for (int i = 0; i < ITILE; ++i) {
      if (mis[i]) {  // wave-uniform branch
        float e = s1s[i] + s2j;
        e = e > 0.f ? e : ALPHA_NS * e;
        const float pv = ((aij[i] & mj) != 0) ? __expf(e) : 0.f;
        pA[w][i][lane] = f32_to_bf16_rne(pv);
      }
    }
    // ---- prefetch tile t+1 (rides across the MFMA phase) ----
    if (t != NN / (JTILE * NWAVE) - 1) {
      const int j0n = ((t + 1) * NWAVE + w) * JTILE;
#pragma unroll
      for (int i = 0; i < ITILE; ++i)
        if (mis[i]) aij[i] = adjp[(long)i * NN + j0n + lane];
      s2j = s2g[b * NN + j0n + lane];
      mj = mask[b * NN + j0n + lane];
    }
    // ---- phase 2: acc[i][d] += P[i][k] * Z[k][d] via 16x16x16 bf16 MFMA ----
#pragma unroll
    for (int ks = 0; ks < 4; ++ks) {
      const int jloc = ks * 16 + kgrp * 4;
      const short4v af = __builtin_bit_cast(
          short4v, *reinterpret_cast<const ushort4v*>(&pA[w][row16][jloc]));
#pragma unroll
      for (int dt = 0; dt < 5; ++dt) {
        const unsigned short* bp =
            zb + (size_t)(dt * 16 + row16) * (BB * NN) + j0c + jloc;
        const short4v bf = __builtin_bit_cast(
            short4v, *reinterpret_cast<const ushort4v*>(bp));
        acc[dt] =
            __builtin_amdgcn_mfma_f32_16x16x16bf16_1k(af, bf, acc[dt], 0, 0, 0);
      }
    }
  }

  // ---- stash per-wave partials ----
  if (row16 == 0) {
#pragma unroll
    for (int r = 0; r < 4; ++r) Lred[w][kgrp * 4 + r] = acc[4][r];
  }
#pragma unroll
  for (int dt = 0; dt < 4; ++dt) {
#pragma unroll
    for (int r = 0; r < 4; ++r)
      accS[w][kgrp * 4 + r][dt * 16 + row16] = acc[dt][r];
  }
  __syncthreads();

  // ---- epilogue: combine waves, divide, ELU, store ----
#pragma unroll
  for (int it = 0; it < 4; ++it) {
    const int i = (tid >> 6) + it * 4;
    const int d = tid & 63;
    const float L = Lred[0][i] + Lred[1][i] + Lred[2][i] + Lred[3][i];
    const float v = accS[0][i][d] + accS[1][i][d] + accS[2][i][d] + accS[3][i][d];
    const float hp = (L != 0.f) ? (v / L) : (zsum[b * DOUT + d] * (1.f / NN));
    const float r = hp > 0.f ? hp : (__expf(hp) - 1.f);
    out[((long)b * NN + i0 + i) * DOUT + d] = r;
  }
}

extern "C" void kernel_launch(void* const* d_in, const int* in_sizes, int n_in,
                              void* d_out, int out_size, void* d_ws, size_t ws_size,
                              hipStream_t stream) {
  const float* h = (const float*)d_in[0];
  const int* adj = (const int*)d_in[1];
  const int* mask = (const int*)d_in[2];
  const float* W = (const float*)d_in[3];
  const float* a = (const float*)d_in[4];
  float* out = (float*)d_out;

  unsigned short* zT = (unsigned short*)d_ws;  // DEXT * B*N * 2B = 2.62 MB
  float* s1 = (float*)((char*)d_ws + (size_t)DEXT * BB * NN * 2);
  float* s2 = s1 + (size_t)BB * NN;
  float* zsum = s2 + (size_t)BB * NN;  // B*DOUT floats

  hipMemsetAsync(zsum, 0, BB * DOUT * sizeof(float), stream);
  gat_zproj<<<dim3(BB * NN / 16), dim3(256), 0, stream>>>(h, W, a, zT, s1, s2,
                                                          zsum);
  gat_attn<<<dim3(NN / ITILE, BB), dim3(256), 0, stream>>>(zT, s1, s2, adj, mask,
                                                           zsum, out);
}

// Round 4
// 87.114 us; speedup vs baseline: 3.6586x; 1.1837x over previous
//
#include <hip/hip_runtime.h>

#define BB 8
#define NN 2048
#define DIN 128
#define DOUT 64
#define ALPHA_NS 0.2f
#define ITILE 16
#define JTILE 64
#define NWAVE 4
#define TTOT (NN / (JTILE * NWAVE))  // 8 tiles per wave

typedef __attribute__((ext_vector_type(4))) short short4v;
typedef __attribute__((ext_vector_type(4))) unsigned short ushort4v;
typedef __attribute__((ext_vector_type(4))) float float4v;

__device__ __forceinline__ unsigned short f32_to_bf16_rne(float x) {
  unsigned u = __builtin_bit_cast(unsigned, x);
  u += 0x7FFFu + ((u >> 16) & 1u);
  return (unsigned short)(u >> 16);
}

// ------ Kernel A: z = h@W (fp32 acc) -> zT2 tiles (bf16), s1, s2, zsum ------
// zT2[(b*32+jb)*64 + d][jj] : 64x64 (d,jj) tiles, jb = j/64, jj = j%64.
__global__ __launch_bounds__(256) void gat_zproj(
    const float* __restrict__ h, const float* __restrict__ W,
    const float* __restrict__ a, unsigned short* __restrict__ zT,
    float* __restrict__ s1, float* __restrict__ s2, float* __restrict__ zsum) {
  const int tid = threadIdx.x;
  const int w = tid >> 6, lane = tid & 63;
  const long r0 = (long)blockIdx.x * 16;
  const int b = blockIdx.x >> 7;  // 128 blocks per batch

  __shared__ float hS[16][DIN];       // 8 KB
  __shared__ float accW[4][16][DOUT]; // 16 KB
  __shared__ float zred[4][DOUT];     // 1 KB

  float Wr[32];
#pragma unroll
  for (int kk = 0; kk < 32; ++kk) Wr[kk] = W[(w * 32 + kk) * DOUT + lane];

  {
    const int r = tid >> 4, c = (tid & 15) * 8;
    const float* src = h + (r0 + r) * DIN + c;
    *reinterpret_cast<float4*>(&hS[r][c]) = *reinterpret_cast<const float4*>(src);
    *reinterpret_cast<float4*>(&hS[r][c + 4]) =
        *reinterpret_cast<const float4*>(src + 4);
  }
  __syncthreads();

#pragma unroll
  for (int r = 0; r < 16; ++r) {
    float acc = 0.f;
#pragma unroll
    for (int k4 = 0; k4 < 8; ++k4) {
      const float4 h4 = *reinterpret_cast<const float4*>(&hS[r][w * 32 + k4 * 4]);
      acc = fmaf(h4.x, Wr[k4 * 4 + 0], acc);
      acc = fmaf(h4.y, Wr[k4 * 4 + 1], acc);
      acc = fmaf(h4.z, Wr[k4 * 4 + 2], acc);
      acc = fmaf(h4.w, Wr[k4 * 4 + 3], acc);
    }
    accW[w][r][lane] = acc;
  }
  __syncthreads();

  float zsp = 0.f;
  unsigned short zt4[4];
#pragma unroll
  for (int it = 0; it < 4; ++it) {
    const int i = w * 4 + it;
    const int d = lane;
    const float zv =
        accW[0][i][d] + accW[1][i][d] + accW[2][i][d] + accW[3][i][d];
    zsp += zv;
    zt4[it] = f32_to_bf16_rne(zv);
    float v1 = zv * a[d];
    float v2 = zv * a[DOUT + d];
#pragma unroll
    for (int off = 32; off; off >>= 1) {
      v1 += __shfl_xor(v1, off);
      v2 += __shfl_xor(v2, off);
    }
    if (lane == 0) {
      s1[r0 + i] = v1;
      s2[r0 + i] = v2;
    }
  }
  // store into tiled layout: lane = d, this block's 16 j's live in one jb tile
  {
    const int bloc = blockIdx.x & 127;     // block index within batch
    const int jb = bloc >> 2;              // 4 blocks per 64-j tile
    const int jj0 = (bloc & 3) * 16;       // j offset inside tile
    ushort4v v;
    v.x = zt4[0]; v.y = zt4[1]; v.z = zt4[2]; v.w = zt4[3];
    const size_t e = ((size_t)(b * (NN / 64) + jb) * DOUT + lane) * 64 + jj0 + w * 4;
    *reinterpret_cast<ushort4v*>(zT + e) = v;
  }
  zred[w][lane] = zsp;
  __syncthreads();
  if (w == 0)
    atomicAdd(&zsum[b * DOUT + lane],
              zred[0][lane] + zred[1][lane] + zred[2][lane] + zred[3][lane]);
}

// ------ Kernel B: masked softmax + PV (bf16 MFMA) + ELU, reg-pipelined ------
__global__ __launch_bounds__(256, 4) void gat_attn(
    const unsigned short* __restrict__ zT, const float* __restrict__ s1g,
    const float* __restrict__ s2g, const int* __restrict__ adj,
    const int* __restrict__ mask, const float* __restrict__ zsum,
    float* __restrict__ out) {
  const int b = blockIdx.y;
  const int i0 = blockIdx.x * ITILE;
  const int tid = threadIdx.x;
  const int w = tid >> 6, lane = tid & 63;
  const int row16 = lane & 15, kgrp = lane >> 4;

  __shared__ unsigned short pA[NWAVE][ITILE][72];  // 9.2 KB
  __shared__ float accS[NWAVE][ITILE][DOUT];       // 16 KB
  __shared__ float Lred[NWAVE][ITILE];
  __shared__ float s1s[ITILE];
  __shared__ int mis[ITILE];

  if (tid < ITILE) {
    s1s[tid] = s1g[b * NN + i0 + tid];
    mis[tid] = mask[b * NN + i0 + tid];
  }
  __syncthreads();

  // zero pA rows for masked-out i once (they never change)
#pragma unroll
  for (int i = 0; i < ITILE; ++i)
    if (!mis[i]) pA[w][i][lane] = 0;

  float4v acc[5];
#pragma unroll
  for (int dt = 0; dt < 5; ++dt) acc[dt] = (float4v){0.f, 0.f, 0.f, 0.f};

  // constant B-fragment of all-ones column 0 -> denominator via MFMA
  const short4v ones =
      (row16 == 0) ? short4v{(short)0x3F80, (short)0x3F80, (short)0x3F80,
                             (short)0x3F80}
                   : short4v{0, 0, 0, 0};

  const int* adjp = adj + ((long)(b * NN + i0)) * NN;
  const unsigned short* ztb = zT + (size_t)b * (NN * DOUT);
  const int lbase = row16 * 64 + kgrp * 4;  // per-lane offset inside a 64x64 tile

  // ---- prologue: prefetch tile 0 (adj, s2/mask, zT frags) ----
  int aij[ITILE];
  {
    const int j0 = w * JTILE;
#pragma unroll
    for (int i = 0; i < ITILE; ++i)
      if (mis[i]) aij[i] = adjp[(long)i * NN + j0 + lane];
  }
  float s2j = s2g[b * NN + w * JTILE + lane];
  int mj = mask[b * NN + w * JTILE + lane];
  short4v bfr[16];
  {
    const unsigned short* zt0 = ztb + (size_t)w * (DOUT * 64) + lbase;
#pragma unroll
    for (int ks = 0; ks < 4; ++ks)
#pragma unroll
      for (int dt = 0; dt < 4; ++dt)
        bfr[ks * 4 + dt] = __builtin_bit_cast(
            short4v,
            *reinterpret_cast<const ushort4v*>(zt0 + dt * 1024 + ks * 16));
  }

#pragma unroll 1
  for (int t = 0; t < TTOT; ++t) {
    // ---- phase 1: scores -> p (bf16) into pA[w][i][j], lane = j ----
#pragma unroll
    for (int i = 0; i < ITILE; ++i) {
      if (mis[i]) {  // block-uniform branch
        float e = s1s[i] + s2j;
        e = e > 0.f ? e : ALPHA_NS * e;
        const float pv = ((aij[i] & mj) != 0) ? __expf(e) : 0.f;
        pA[w][i][lane] = f32_to_bf16_rne(pv);
      }
    }
    // ---- issue adj/s2/mask prefetch for t+1 (completes during MFMA phase) ----
    if (t + 1 < TTOT) {
      const int j0n = ((t + 1) * NWAVE + w) * JTILE;
#pragma unroll
      for (int i = 0; i < ITILE; ++i)
        if (mis[i]) aij[i] = adjp[(long)i * NN + j0n + lane];
      s2j = s2g[b * NN + j0n + lane];
      mj = mask[b * NN + j0n + lane];
    }
    // ---- phase 2: MFMA over prefetched B-fragments (no loads in here) ----
#pragma unroll
    for (int ks = 0; ks < 4; ++ks) {
      const short4v af = __builtin_bit_cast(
          short4v,
          *reinterpret_cast<const ushort4v*>(&pA[w][row16][ks * 16 + kgrp * 4]));
      acc[4] = __builtin_amdgcn_mfma_f32_16x16x16bf16_1k(af, ones, acc[4], 0, 0, 0);
#pragma unroll
      for (int dt = 0; dt < 4; ++dt)
        acc[dt] = __builtin_amdgcn_mfma_f32_16x16x16bf16_1k(af, bfr[ks * 4 + dt],
                                                            acc[dt], 0, 0, 0);
    }
    // ---- issue zT fragment prefetch for t+1 ----
    if (t + 1 < TTOT) {
      const unsigned short* ztn =
          ztb + (size_t)((t + 1) * NWAVE + w) * (DOUT * 64) + lbase;
#pragma unroll
      for (int ks = 0; ks < 4; ++ks)
#pragma unroll
        for (int dt = 0; dt < 4; ++dt)
          bfr[ks * 4 + dt] = __builtin_bit_cast(
              short4v,
              *reinterpret_cast<const ushort4v*>(ztn + dt * 1024 + ks * 16));
    }
  }

  // ---- stash per-wave partials ----
  if (row16 == 0) {
#pragma unroll
    for (int r = 0; r < 4; ++r) Lred[w][kgrp * 4 + r] = acc[4][r];
  }
#pragma unroll
  for (int dt = 0; dt < 4; ++dt) {
#pragma unroll
    for (int r = 0; r < 4; ++r)
      accS[w][kgrp * 4 + r][dt * 16 + row16] = acc[dt][r];
  }
  __syncthreads();

  // ---- epilogue: combine waves, divide, ELU, store ----
#pragma unroll
  for (int it = 0; it < 4; ++it) {
    const int i = (tid >> 6) + it * 4;
    const int d = tid & 63;
    const float L = Lred[0][i] + Lred[1][i] + Lred[2][i] + Lred[3][i];
    const float v = accS[0][i][d] + accS[1][i][d] + accS[2][i][d] + accS[3][i][d];
    const float hp = (L != 0.f) ? (v / L) : (zsum[b * DOUT + d] * (1.f / NN));
    const float r = hp > 0.f ? hp : (__expf(hp) - 1.f);
    out[((long)b * NN + i0 + i) * DOUT + d] = r;
  }
}

extern "C" void kernel_launch(void* const* d_in, const int* in_sizes, int n_in,
                              void* d_out, int out_size, void* d_ws, size_t ws_size,
                              hipStream_t stream) {
  const float* h = (const float*)d_in[0];
  const int* adj = (const int*)d_in[1];
  const int* mask = (const int*)d_in[2];
  const float* W = (const float*)d_in[3];
  const float* a = (const float*)d_in[4];
  float* out = (float*)d_out;

  unsigned short* zT = (unsigned short*)d_ws;  // B*N*DOUT bf16 = 2 MB
  float* s1 = (float*)((char*)d_ws + (size_t)BB * NN * DOUT * 2);
  float* s2 = s1 + (size_t)BB * NN;
  float* zsum = s2 + (size_t)BB * NN;  // B*DOUT floats

  hipMemsetAsync(zsum, 0, BB * DOUT * sizeof(float), stream);
  gat_zproj<<<dim3(BB * NN / 16), dim3(256), 0, stream>>>(h, W, a, zT, s1, s2,
                                                          zsum);
  gat_attn<<<dim3(NN / ITILE, BB), dim3(256), 0, stream>>>(zT, s1, s2, adj, mask,
                                                           zsum, out);
}